// Round 13
// baseline (3694.949 us; speedup 1.0000x reference)
//
#include <hip/hip_runtime.h>
#include <cstdint>
#include <cstddef>

#define NFILT 40
#define NBINS 257
#define HID   64
#define BB    64      // batch
#define TT    2000    // time
#define GATES 256     // 4*HID
#define MTOT  (BB*TT) // 128000 rows

// ---------- activations ----------
__device__ __forceinline__ float sigm(float x) {
  return 1.0f / (1.0f + __expf(-x));
}

// quad butterfly via DPP (VALU pipe, no LDS): after bfly2(bfly1(x)) every lane
// of each 4-lane quad holds the quad sum. (numerically verified R5/R11/R12)
__device__ __forceinline__ float bfly1(float x) {
  int i = __builtin_amdgcn_mov_dpp(__float_as_int(x), 0xB1, 0xF, 0xF, true); // quad_perm [1,0,3,2]
  return x + __int_as_float(i);
}
__device__ __forceinline__ float bfly2(float x) {
  int i = __builtin_amdgcn_mov_dpp(__float_as_int(x), 0x4E, 0xF, 0xF, true); // quad_perm [2,3,0,1]
  return x + __int_as_float(i);
}
// quad broadcast: every lane gets lane q's value (quad_perm [q,q,q,q])
#define QB(x, ctrl) __int_as_float(__builtin_amdgcn_mov_dpp(__float_as_int(x), (ctrl), 0xF, 0xF, true))

__device__ __forceinline__ float dot16(const float4* w, float4 a, float4 b,
                                       float4 c2, float4 d2, float acc) {
  acc = fmaf(a.x, w[0].x, acc);  acc = fmaf(a.y, w[0].y, acc);
  acc = fmaf(a.z, w[0].z, acc);  acc = fmaf(a.w, w[0].w, acc);
  acc = fmaf(b.x, w[1].x, acc);  acc = fmaf(b.y, w[1].y, acc);
  acc = fmaf(b.z, w[1].z, acc);  acc = fmaf(b.w, w[1].w, acc);
  acc = fmaf(c2.x, w[2].x, acc); acc = fmaf(c2.y, w[2].y, acc);
  acc = fmaf(c2.z, w[2].z, acc); acc = fmaf(c2.w, w[2].w, acc);
  acc = fmaf(d2.x, w[3].x, acc); acc = fmaf(d2.y, w[3].y, acc);
  acc = fmaf(d2.z, w[3].z, acc); acc = fmaf(d2.w, w[3].w, acc);
  return acc;
}

// ---------- kernel 1: build fbank (40x257) + per-filter support bounds ----------
__global__ void k_fbank(const float* __restrict__ binpoints,
                        float* __restrict__ fbank,
                        int* __restrict__ lohi /*[2*NFILT]*/) {
  __shared__ float b[NFILT + 2];
  int tid = threadIdx.x;
  if (tid < NFILT + 2) b[tid] = binpoints[tid];
  __syncthreads();
  if (tid < NFILT) {
    if (tid == NFILT - 1) { lohi[tid] = 0; lohi[NFILT + tid] = 0; }
    else {
      int lo = (int)floorf(b[tid]);
      int hi = (int)floorf(b[tid + 2]);
      if (lo < 0) lo = 0;
      if (hi > NBINS) hi = NBINS;
      lohi[tid] = lo; lohi[NFILT + tid] = hi;
    }
  }
  for (int idx = tid; idx < NFILT * NBINS; idx += blockDim.x) {
    int f = idx / NBINS, i = idx - f * NBINS;
    float bj = b[f], bj1 = b[f + 1], bj2 = b[f + 2];
    float fb0 = floorf(bj), fb1 = floorf(bj1), fb2 = floorf(bj2);
    float fi = (float)i;
    bool rise = (fi >= fb0) && (fi < fb1);
    bool fall = (fi >= fb1) && (fi < fb2);
    float d1 = bj1 - bj;  d1 = (d1 > 0.f) ? d1 : 1.f;
    float d2 = bj2 - bj1; d2 = (d2 > 0.f) ? d2 : 1.f;
    float rv = (fi - bj)  / (d1 * d1);
    float fv = (bj2 - fi) / (d2 * d2);
    float v = fall ? fv : (rise ? rv : 0.f);
    if (f == NFILT - 1) v = 0.f;
    fbank[idx] = v;
  }
}

// ---------- kernel 2: featurize  h0[bt][f] = log(filt + 1e-10) ----------
__global__ __launch_bounds__(64) void k_feat(const float* __restrict__ x,
                                             const float* __restrict__ fbank,
                                             const int* __restrict__ lohi,
                                             float* __restrict__ h0) {
  int bt = blockIdx.x;
  __shared__ float xs[NBINS];
  const float* xr = x + (size_t)bt * NBINS;
  for (int i = threadIdx.x; i < NBINS; i += 64) xs[i] = xr[i];
  __syncthreads();
  int f = threadIdx.x;
  if (f < NFILT) {
    float acc = 0.f;
    int lo = lohi[f], hi = lohi[NFILT + f];
    for (int i = lo; i < hi; ++i) acc = fmaf(xs[i], fbank[f * NBINS + i], acc);
    float val = (f == 0) ? xs[0] : acc;
    h0[(size_t)bt * NFILT + f] = logf(val + 1e-10f);
  }
}

// ---------- kernel 3: fp32 GEMM, 128x64 tile, 8x4 micro (REVERTED to R11 form:
// the 128x128 tile of R12 was ~140 us slower overall -- less latency-hiding
// occupancy per CU outweighed the better VALU:LDS ratio) ----------
template <int K, int BK>
__global__ __launch_bounds__(256) void k_gemm(const float* __restrict__ Hm,   // [MTOT][K]
                                              const float* __restrict__ W,    // [2][256][K]
                                              const float* __restrict__ bih,  // [2][256]
                                              const float* __restrict__ bhh,  // [2][256]
                                              float* __restrict__ pre) {      // [2][MTOT][256]
  constexpr int BM = 128, BN = 64;
  __shared__ float Hs[BK][BM + 4];
  __shared__ float Ws[BK][BN + 4];
  const int d  = blockIdx.z;
  const int m0 = blockIdx.x * BM;
  const int g0 = blockIdx.y * BN;
  const int tid = threadIdx.x;
  const int tx = tid & 15, ty = tid >> 4;

  float acc[8][4];
#pragma unroll
  for (int r = 0; r < 8; ++r)
#pragma unroll
    for (int j = 0; j < 4; ++j) acc[r][j] = 0.f;

  for (int k0 = 0; k0 < K; k0 += BK) {
    constexpr int HL = BM * BK / 256;
#pragma unroll
    for (int i = 0; i < HL; ++i) {
      int flat = tid + i * 256;
      int r = flat / BK, kk = flat - r * BK;
      Hs[kk][r] = Hm[(size_t)(m0 + r) * K + k0 + kk];
    }
    constexpr int WL = BN * BK / 256;
#pragma unroll
    for (int i = 0; i < WL; ++i) {
      int flat = tid + i * 256;
      int r = flat / BK, kk = flat - r * BK;
      Ws[kk][r] = W[((size_t)d * GATES + g0 + r) * K + k0 + kk];
    }
    __syncthreads();
#pragma unroll
    for (int kk = 0; kk < BK; ++kk) {
      const float4 wv  = *(const float4*)&Ws[kk][tx * 4];
      const float4 hv0 = *(const float4*)&Hs[kk][ty * 8];
      const float4 hv1 = *(const float4*)&Hs[kk][ty * 8 + 4];
      const float hr[8] = {hv0.x, hv0.y, hv0.z, hv0.w, hv1.x, hv1.y, hv1.z, hv1.w};
#pragma unroll
      for (int r = 0; r < 8; ++r) {
        acc[r][0] = fmaf(hr[r], wv.x, acc[r][0]);
        acc[r][1] = fmaf(hr[r], wv.y, acc[r][1]);
        acc[r][2] = fmaf(hr[r], wv.z, acc[r][2]);
        acc[r][3] = fmaf(hr[r], wv.w, acc[r][3]);
      }
    }
    __syncthreads();
  }

  const int gcol = g0 + tx * 4;
  const float4 bi = *(const float4*)&bih[d * GATES + gcol];
  const float4 bh = *(const float4*)&bhh[d * GATES + gcol];
  const float bx = bi.x + bh.x, by = bi.y + bh.y, bz = bi.z + bh.z, bw = bi.w + bh.w;
#pragma unroll
  for (int r = 0; r < 8; ++r) {
    size_t m = (size_t)(m0 + ty * 8 + r);
    float4 o = {acc[r][0] + bx, acc[r][1] + by, acc[r][2] + bz, acc[r][3] + bw};
    *(float4*)&pre[((size_t)d * MTOT + m) * GATES + gcol] = o;
  }
}

// ---------- kernel 4: recurrent LSTM, quad-per-unit, TWO chains per 512-thread block ----------
// R12's step body verbatim (800 us, 960 cyc/step: ~230 issue + ~730 stall).
// NEW: both directions (d=0,1) of batch b live in one block. Each SIMD hosts
// 2 waves from DIFFERENT chains -> when chain A's wave stalls (LDS round-trip,
// TRANS latency, DPP waits), chain B's wave issues. SMT hides the ~730-cyc
// stall; per-SIMD issue doubles to ~460 cyc/step, still far below 960.
// waves_per_eu(2,2): budget 256 VGPR/wave, kernel needs ~132 -> weights stay
// resident (2x132 < 512-reg file). Shared s_barrier now syncs 8 waves; both
// chains have identical work so added skew is negligible.
__global__ __attribute__((amdgpu_waves_per_eu(2, 2)))
__launch_bounds__(512) void k_lstmq(const float* __restrict__ pre, // [2][B*T][256]
                                    const float* __restrict__ whh, // [2][256][64]
                                    float* __restrict__ hout,      // [B][T][128]
                                    float* __restrict__ out,       // [B][128]
                                    int final_layer) {
  const int b   = blockIdx.x;
  const int tid = threadIdx.x;
  const int d   = tid >> 8;          // chain (direction) 0/1
  const int wl  = (tid >> 6) & 3;    // wave within chain
  const int l   = tid & 63;
  const int uu  = wl * 16 + (l >> 2); // hidden unit owned by this quad
  const int p   = l & 3;              // k-slice / gate index
  const int p16 = p * 16;

  __shared__ __align__(16) float hs[2][2][HID];   // [chain][parity][unit]

  // weights: wq[q][c] = W[d][q*64+uu][16p + 4c .. +3]  (64 floats/lane)
  float4 wq[4][4];
#pragma unroll
  for (int q = 0; q < 4; ++q) {
    const float4* wr = (const float4*)(whh + ((size_t)d * GATES + q * HID + uu) * HID + p16);
#pragma unroll
    for (int c2 = 0; c2 < 4; ++c2) wq[q][c2] = wr[c2];
  }
  {
    float* wf = (float*)&wq[0][0];
#pragma unroll
    for (int i = 0; i < 64; ++i) asm volatile("" : "+v"(wf[i]));  // pin resident
  }
  // per-lane activation constants: gate 2 (p==2) is tanh = 2*sigm(2x)-1
  const float sA = (p == 2) ? 2.f : 1.f;   // input scale
  const float aA = (p == 2) ? 2.f : 1.f;   // output scale
  const float aB = (p == 2) ? -1.f : 0.f;  // output bias
  const bool  p1 = (p & 1) != 0;
  const bool  p2 = (p & 2) != 0;

  if ((tid & 255) < HID) { hs[d][0][tid & 63] = 0.f; hs[d][1][tid & 63] = 0.f; }
  float c = 0.f, sum = 0.f;
  __syncthreads();   // one-time full barrier

  const int t0 = d ? (TT - 1) : 0;
  const int dt = d ? -1 : 1;
  const float* pp = pre + ((size_t)d * MTOT + (size_t)b * TT + t0) * GATES + (p * HID + uu);
  const ptrdiff_t pstr = (ptrdiff_t)dt * GATES;

  float pf0 = pp[0], pf1 = pp[pstr], pf2 = pp[pstr * 2], pf3 = pp[pstr * 3];

#define LSTM_STEP(TK, PAR, PF)                                                  \
  do {                                                                          \
    const float4* h4 = (const float4*)&hs[d][PAR][p16];                         \
    const float4 hA = h4[0], hB = h4[1], hC = h4[2], hD = h4[3];                \
    float a0 = dot16(wq[0], hA, hB, hC, hD, 0.f);                               \
    float a1 = dot16(wq[1], hA, hB, hC, hD, 0.f);                               \
    float a2 = dot16(wq[2], hA, hB, hC, hD, 0.f);                               \
    float a3 = dot16(wq[3], hA, hB, hC, hD, 0.f);                               \
    a0 = bfly2(bfly1(a0)); a1 = bfly2(bfly1(a1));                               \
    a2 = bfly2(bfly1(a2)); a3 = bfly2(bfly1(a3));                               \
    const float t02 = p2 ? a2 : a0;                                             \
    const float t13 = p2 ? a3 : a1;                                             \
    const float zsel = (p1 ? t13 : t02) + (PF);                                 \
    const float act = fmaf(sigm(zsel * sA), aA, aB);                            \
    const float ig = QB(act, 0x00), fg = QB(act, 0x55);                         \
    const float gg = QB(act, 0xAA), og = QB(act, 0xFF);                         \
    c = fmaf(fg, c, ig * gg);                                                   \
    const float tc = fmaf(sigm(2.f * c), 2.f, -1.f);                            \
    const float hvv = og * tc;                                                  \
    if (p == 0) hs[d][(PAR) ^ 1][uu] = hvv;                                     \
    asm volatile("s_waitcnt lgkmcnt(0)\n\ts_barrier" ::: "memory");             \
    if (final_layer) sum += hvv;                                                \
    else if (p == 0)                                                            \
      hout[((size_t)b * TT + (size_t)(t0 + dt * (TK))) * (2 * HID) + d * HID + uu] = hvv; \
  } while (0)

  for (int t = 0; t < TT; t += 4) {
    LSTM_STEP(t + 0, 0, pf0);
    { int ip = t + 4; if (ip >= TT) ip = 0; pf0 = pp[pstr * (ptrdiff_t)ip]; }
    LSTM_STEP(t + 1, 1, pf1);
    { int ip = t + 5; if (ip >= TT) ip = 0; pf1 = pp[pstr * (ptrdiff_t)ip]; }
    LSTM_STEP(t + 2, 0, pf2);
    { int ip = t + 6; if (ip >= TT) ip = 0; pf2 = pp[pstr * (ptrdiff_t)ip]; }
    LSTM_STEP(t + 3, 1, pf3);
    { int ip = t + 7; if (ip >= TT) ip = 0; pf3 = pp[pstr * (ptrdiff_t)ip]; }
  }
#undef LSTM_STEP

  if (final_layer && p == 0) out[b * (2 * HID) + d * HID + uu] = sum * (1.0f / (float)TT);
}

// ---------- launch ----------
extern "C" void kernel_launch(void* const* d_in, const int* in_sizes, int n_in,
                              void* d_out, int out_size, void* d_ws, size_t ws_size,
                              hipStream_t stream) {
  const float* x         = (const float*)d_in[0];
  const float* binpoints = (const float*)d_in[1];
  const float* w_ih[3] = {(const float*)d_in[2], (const float*)d_in[6],  (const float*)d_in[10]};
  const float* w_hh[3] = {(const float*)d_in[3], (const float*)d_in[7],  (const float*)d_in[11]};
  const float* b_ih[3] = {(const float*)d_in[4], (const float*)d_in[8],  (const float*)d_in[12]};
  const float* b_hh[3] = {(const float*)d_in[5], (const float*)d_in[9],  (const float*)d_in[13]};
  float* out = (float*)d_out;

  // workspace layout (~349 MB):
  //   pre  : 2*MTOT*256 f32 = 262,144,000 B
  //   Hbuf : MTOT*128 f32   =  65,536,000 B
  //   h0   : MTOT*40 f32    =  20,480,000 B
  //   fbank: 40*257 f32, lohi: 80 i32
  float* pre   = (float*)d_ws;
  float* Hbuf  = pre  + (size_t)2 * MTOT * GATES;
  float* h0    = Hbuf + (size_t)MTOT * 128;
  float* fbank = h0   + (size_t)MTOT * NFILT;
  int*   lohi  = (int*)(fbank + NFILT * NBINS);

  k_fbank<<<1, 256, 0, stream>>>(binpoints, fbank, lohi);
  k_feat<<<MTOT, 64, 0, stream>>>(x, fbank, lohi, h0);

  // layer 0 (K=40)
  k_gemm<40, 40><<<dim3(MTOT / 128, GATES / 64, 2), 256, 0, stream>>>(h0, w_ih[0], b_ih[0], b_hh[0], pre);
  k_lstmq<<<BB, 512, 0, stream>>>(pre, w_hh[0], Hbuf, out, 0);

  // layer 1 (K=128)
  k_gemm<128, 32><<<dim3(MTOT / 128, GATES / 64, 2), 256, 0, stream>>>(Hbuf, w_ih[1], b_ih[1], b_hh[1], pre);
  k_lstmq<<<BB, 512, 0, stream>>>(pre, w_hh[1], Hbuf, out, 0);

  // layer 2 (K=128)
  k_gemm<128, 32><<<dim3(MTOT / 128, GATES / 64, 2), 256, 0, stream>>>(Hbuf, w_ih[2], b_ih[2], b_hh[2], pre);
  k_lstmq<<<BB, 512, 0, stream>>>(pre, w_hh[2], Hbuf, out, 1);
}

// Round 14
// 3024.316 us; speedup vs baseline: 1.2217x; 1.2217x over previous
//
#include <hip/hip_runtime.h>
#include <cstdint>
#include <cstddef>

#define NFILT 40
#define NBINS 257
#define HID   64
#define BB    64      // batch
#define TT    2000    // time
#define GATES 256     // 4*HID
#define MTOT  (BB*TT) // 128000 rows

// ---------- activations ----------
__device__ __forceinline__ float sigm(float x) {
  return 1.0f / (1.0f + __expf(-x));
}

// quad butterfly via DPP (VALU pipe, no LDS): after bfly2(bfly1(x)) every lane
// of each 4-lane quad holds the quad sum. (numerically verified R5/R11/R12)
__device__ __forceinline__ float bfly1(float x) {
  int i = __builtin_amdgcn_mov_dpp(__float_as_int(x), 0xB1, 0xF, 0xF, true); // quad_perm [1,0,3,2]
  return x + __int_as_float(i);
}
__device__ __forceinline__ float bfly2(float x) {
  int i = __builtin_amdgcn_mov_dpp(__float_as_int(x), 0x4E, 0xF, 0xF, true); // quad_perm [2,3,0,1]
  return x + __int_as_float(i);
}
// quad broadcast: every lane gets lane q's value (quad_perm [q,q,q,q])
#define QB(x, ctrl) __int_as_float(__builtin_amdgcn_mov_dpp(__float_as_int(x), (ctrl), 0xF, 0xF, true))

__device__ __forceinline__ float dot16(const float4* w, float4 a, float4 b,
                                       float4 c2, float4 d2, float acc) {
  acc = fmaf(a.x, w[0].x, acc);  acc = fmaf(a.y, w[0].y, acc);
  acc = fmaf(a.z, w[0].z, acc);  acc = fmaf(a.w, w[0].w, acc);
  acc = fmaf(b.x, w[1].x, acc);  acc = fmaf(b.y, w[1].y, acc);
  acc = fmaf(b.z, w[1].z, acc);  acc = fmaf(b.w, w[1].w, acc);
  acc = fmaf(c2.x, w[2].x, acc); acc = fmaf(c2.y, w[2].y, acc);
  acc = fmaf(c2.z, w[2].z, acc); acc = fmaf(c2.w, w[2].w, acc);
  acc = fmaf(d2.x, w[3].x, acc); acc = fmaf(d2.y, w[3].y, acc);
  acc = fmaf(d2.z, w[3].z, acc); acc = fmaf(d2.w, w[3].w, acc);
  return acc;
}

// ---------- kernel 1: build fbank (40x257) + per-filter support bounds ----------
__global__ void k_fbank(const float* __restrict__ binpoints,
                        float* __restrict__ fbank,
                        int* __restrict__ lohi /*[2*NFILT]*/) {
  __shared__ float b[NFILT + 2];
  int tid = threadIdx.x;
  if (tid < NFILT + 2) b[tid] = binpoints[tid];
  __syncthreads();
  if (tid < NFILT) {
    if (tid == NFILT - 1) { lohi[tid] = 0; lohi[NFILT + tid] = 0; }
    else {
      int lo = (int)floorf(b[tid]);
      int hi = (int)floorf(b[tid + 2]);
      if (lo < 0) lo = 0;
      if (hi > NBINS) hi = NBINS;
      lohi[tid] = lo; lohi[NFILT + tid] = hi;
    }
  }
  for (int idx = tid; idx < NFILT * NBINS; idx += blockDim.x) {
    int f = idx / NBINS, i = idx - f * NBINS;
    float bj = b[f], bj1 = b[f + 1], bj2 = b[f + 2];
    float fb0 = floorf(bj), fb1 = floorf(bj1), fb2 = floorf(bj2);
    float fi = (float)i;
    bool rise = (fi >= fb0) && (fi < fb1);
    bool fall = (fi >= fb1) && (fi < fb2);
    float d1 = bj1 - bj;  d1 = (d1 > 0.f) ? d1 : 1.f;
    float d2 = bj2 - bj1; d2 = (d2 > 0.f) ? d2 : 1.f;
    float rv = (fi - bj)  / (d1 * d1);
    float fv = (bj2 - fi) / (d2 * d2);
    float v = fall ? fv : (rise ? rv : 0.f);
    if (f == NFILT - 1) v = 0.f;
    fbank[idx] = v;
  }
}

// ---------- kernel 2: featurize, 4 rows per 256-thread block (one wave each) ----------
__global__ __launch_bounds__(256) void k_feat(const float* __restrict__ x,
                                              const float* __restrict__ fbank,
                                              const int* __restrict__ lohi,
                                              float* __restrict__ h0) {
  const int wv   = threadIdx.x >> 6;
  const int lane = threadIdx.x & 63;
  const int bt   = blockIdx.x * 4 + wv;
  __shared__ float xs[4][NBINS];
  const float* xr = x + (size_t)bt * NBINS;
  for (int i = lane; i < NBINS; i += 64) xs[wv][i] = xr[i];
  __syncthreads();
  if (lane < NFILT) {
    float acc = 0.f;
    int lo = lohi[lane], hi = lohi[NFILT + lane];
    for (int i = lo; i < hi; ++i) acc = fmaf(xs[wv][i], fbank[lane * NBINS + i], acc);
    float val = (lane == 0) ? xs[wv][0] : acc;
    h0[(size_t)bt * NFILT + lane] = logf(val + 1e-10f);
  }
}

// ---------- kernel 3: fp32 GEMM, 128x64 tile, 8x4 micro (proven-best R11/R13 form) ----------
template <int K, int BK>
__global__ __launch_bounds__(256) void k_gemm(const float* __restrict__ Hm,   // [MTOT][K]
                                              const float* __restrict__ W,    // [2][256][K]
                                              const float* __restrict__ bih,  // [2][256]
                                              const float* __restrict__ bhh,  // [2][256]
                                              float* __restrict__ pre) {      // [2][MTOT][256]
  constexpr int BM = 128, BN = 64;
  __shared__ float Hs[BK][BM + 4];
  __shared__ float Ws[BK][BN + 4];
  const int d  = blockIdx.z;
  const int m0 = blockIdx.x * BM;
  const int g0 = blockIdx.y * BN;
  const int tid = threadIdx.x;
  const int tx = tid & 15, ty = tid >> 4;

  float acc[8][4];
#pragma unroll
  for (int r = 0; r < 8; ++r)
#pragma unroll
    for (int j = 0; j < 4; ++j) acc[r][j] = 0.f;

  for (int k0 = 0; k0 < K; k0 += BK) {
    constexpr int HL = BM * BK / 256;
#pragma unroll
    for (int i = 0; i < HL; ++i) {
      int flat = tid + i * 256;
      int r = flat / BK, kk = flat - r * BK;
      Hs[kk][r] = Hm[(size_t)(m0 + r) * K + k0 + kk];
    }
    constexpr int WL = BN * BK / 256;
#pragma unroll
    for (int i = 0; i < WL; ++i) {
      int flat = tid + i * 256;
      int r = flat / BK, kk = flat - r * BK;
      Ws[kk][r] = W[((size_t)d * GATES + g0 + r) * K + k0 + kk];
    }
    __syncthreads();
#pragma unroll
    for (int kk = 0; kk < BK; ++kk) {
      const float4 wv  = *(const float4*)&Ws[kk][tx * 4];
      const float4 hv0 = *(const float4*)&Hs[kk][ty * 8];
      const float4 hv1 = *(const float4*)&Hs[kk][ty * 8 + 4];
      const float hr[8] = {hv0.x, hv0.y, hv0.z, hv0.w, hv1.x, hv1.y, hv1.z, hv1.w};
#pragma unroll
      for (int r = 0; r < 8; ++r) {
        acc[r][0] = fmaf(hr[r], wv.x, acc[r][0]);
        acc[r][1] = fmaf(hr[r], wv.y, acc[r][1]);
        acc[r][2] = fmaf(hr[r], wv.z, acc[r][2]);
        acc[r][3] = fmaf(hr[r], wv.w, acc[r][3]);
      }
    }
    __syncthreads();
  }

  const int gcol = g0 + tx * 4;
  const float4 bi = *(const float4*)&bih[d * GATES + gcol];
  const float4 bh = *(const float4*)&bhh[d * GATES + gcol];
  const float bx = bi.x + bh.x, by = bi.y + bh.y, bz = bi.z + bh.z, bw = bi.w + bh.w;
#pragma unroll
  for (int r = 0; r < 8; ++r) {
    size_t m = (size_t)(m0 + ty * 8 + r);
    float4 o = {acc[r][0] + bx, acc[r][1] + by, acc[r][2] + bz, acc[r][3] + bw};
    *(float4*)&pre[((size_t)d * MTOT + m) * GATES + gcol] = o;
  }
}

// ---------- kernel 4: recurrent LSTM, quad-per-unit, ONE chain per 256-thread block ----------
// VERBATIM round-12 configuration (proven 800 us/dispatch, VGPR 132):
//  * 4 waves/block, 1 wave/SIMD, 128 blocks; waves_per_eu(1,1) + "+v" pin keeps
//    the 64 weights/lane VGPR-resident (R8/R10 proven).
//  * quad DPP butterfly completes all 4 gate sums in-register; ONE activation
//    per lane (sigma/tanh unified, per-lane hoisted constants); 4 DPP quad
//    broadcasts deliver ig/fg/gg/og; pre added once post-butterfly.
//  * parity double-buffered hs; raw asm "lgkmcnt(0); s_barrier" (no vmcnt
//    drain -> 4-deep HBM prefetch stays in flight). ONE LDS round-trip + ONE
//    barrier per step.
// R13's 2-chains/block regressed (VGPR 88 = weights demoted at (2,2) budget;
// 8-wave barrier coupling) -- do NOT re-merge chains into one block.
__global__ __attribute__((amdgpu_waves_per_eu(1, 1)))
__launch_bounds__(256) void k_lstmq(const float* __restrict__ pre, // [2][B*T][256]
                                    const float* __restrict__ whh, // [2][256][64]
                                    float* __restrict__ hout,      // [B][T][128]
                                    float* __restrict__ out,       // [B][128]
                                    int final_layer) {
  const int b   = blockIdx.x;
  const int d   = blockIdx.y;
  const int tid = threadIdx.x;
  const int wl  = tid >> 6;          // wave 0..3
  const int l   = tid & 63;
  const int uu  = wl * 16 + (l >> 2); // hidden unit owned by this quad
  const int p   = l & 3;              // k-slice / gate index
  const int p16 = p * 16;

  __shared__ __align__(16) float hs[2][HID];   // parity double-buffered h

  // weights: wq[q][c] = W[d][q*64+uu][16p + 4c .. +3]  (64 floats/lane)
  float4 wq[4][4];
#pragma unroll
  for (int q = 0; q < 4; ++q) {
    const float4* wr = (const float4*)(whh + ((size_t)d * GATES + q * HID + uu) * HID + p16);
#pragma unroll
    for (int c2 = 0; c2 < 4; ++c2) wq[q][c2] = wr[c2];
  }
  {
    float* wf = (float*)&wq[0][0];
#pragma unroll
    for (int i = 0; i < 64; ++i) asm volatile("" : "+v"(wf[i]));  // pin resident
  }
  // per-lane activation constants: gate 2 (p==2) is tanh = 2*sigm(2x)-1
  const float sA = (p == 2) ? 2.f : 1.f;   // input scale
  const float aA = (p == 2) ? 2.f : 1.f;   // output scale
  const float aB = (p == 2) ? -1.f : 0.f;  // output bias
  const bool  p1 = (p & 1) != 0;
  const bool  p2 = (p & 2) != 0;

  if (tid < HID) { hs[0][tid] = 0.f; hs[1][tid] = 0.f; }
  float c = 0.f, sum = 0.f;
  __syncthreads();   // one-time full barrier

  const int t0 = d ? (TT - 1) : 0;
  const int dt = d ? -1 : 1;
  const float* pp = pre + ((size_t)d * MTOT + (size_t)b * TT + t0) * GATES + (p * HID + uu);
  const ptrdiff_t pstr = (ptrdiff_t)dt * GATES;

  float pf0 = pp[0], pf1 = pp[pstr], pf2 = pp[pstr * 2], pf3 = pp[pstr * 3];

#define LSTM_STEP(TK, PAR, PF)                                                  \
  do {                                                                          \
    const float4* h4 = (const float4*)&hs[PAR][p16];                            \
    const float4 hA = h4[0], hB = h4[1], hC = h4[2], hD = h4[3];                \
    float a0 = dot16(wq[0], hA, hB, hC, hD, 0.f);                               \
    float a1 = dot16(wq[1], hA, hB, hC, hD, 0.f);                               \
    float a2 = dot16(wq[2], hA, hB, hC, hD, 0.f);                               \
    float a3 = dot16(wq[3], hA, hB, hC, hD, 0.f);                               \
    a0 = bfly2(bfly1(a0)); a1 = bfly2(bfly1(a1));                               \
    a2 = bfly2(bfly1(a2)); a3 = bfly2(bfly1(a3));                               \
    const float t02 = p2 ? a2 : a0;                                             \
    const float t13 = p2 ? a3 : a1;                                             \
    const float zsel = (p1 ? t13 : t02) + (PF);                                 \
    const float act = fmaf(sigm(zsel * sA), aA, aB);                            \
    const float ig = QB(act, 0x00), fg = QB(act, 0x55);                         \
    const float gg = QB(act, 0xAA), og = QB(act, 0xFF);                         \
    c = fmaf(fg, c, ig * gg);                                                   \
    const float tc = fmaf(sigm(2.f * c), 2.f, -1.f);                            \
    const float hvv = og * tc;                                                  \
    if (p == 0) hs[(PAR) ^ 1][uu] = hvv;                                        \
    asm volatile("s_waitcnt lgkmcnt(0)\n\ts_barrier" ::: "memory");             \
    if (final_layer) sum += hvv;                                                \
    else if (p == 0)                                                            \
      hout[((size_t)b * TT + (size_t)(t0 + dt * (TK))) * (2 * HID) + d * HID + uu] = hvv; \
  } while (0)

  for (int t = 0; t < TT; t += 4) {
    LSTM_STEP(t + 0, 0, pf0);
    { int ip = t + 4; if (ip >= TT) ip = 0; pf0 = pp[pstr * (ptrdiff_t)ip]; }
    LSTM_STEP(t + 1, 1, pf1);
    { int ip = t + 5; if (ip >= TT) ip = 0; pf1 = pp[pstr * (ptrdiff_t)ip]; }
    LSTM_STEP(t + 2, 0, pf2);
    { int ip = t + 6; if (ip >= TT) ip = 0; pf2 = pp[pstr * (ptrdiff_t)ip]; }
    LSTM_STEP(t + 3, 1, pf3);
    { int ip = t + 7; if (ip >= TT) ip = 0; pf3 = pp[pstr * (ptrdiff_t)ip]; }
  }
#undef LSTM_STEP

  if (final_layer && p == 0) out[b * (2 * HID) + d * HID + uu] = sum * (1.0f / (float)TT);
}

// ---------- launch ----------
extern "C" void kernel_launch(void* const* d_in, const int* in_sizes, int n_in,
                              void* d_out, int out_size, void* d_ws, size_t ws_size,
                              hipStream_t stream) {
  const float* x         = (const float*)d_in[0];
  const float* binpoints = (const float*)d_in[1];
  const float* w_ih[3] = {(const float*)d_in[2], (const float*)d_in[6],  (const float*)d_in[10]};
  const float* w_hh[3] = {(const float*)d_in[3], (const float*)d_in[7],  (const float*)d_in[11]};
  const float* b_ih[3] = {(const float*)d_in[4], (const float*)d_in[8],  (const float*)d_in[12]};
  const float* b_hh[3] = {(const float*)d_in[5], (const float*)d_in[9],  (const float*)d_in[13]};
  float* out = (float*)d_out;

  // workspace layout (~349 MB):
  //   pre  : 2*MTOT*256 f32 = 262,144,000 B
  //   Hbuf : MTOT*128 f32   =  65,536,000 B
  //   h0   : MTOT*40 f32    =  20,480,000 B
  //   fbank: 40*257 f32, lohi: 80 i32
  float* pre   = (float*)d_ws;
  float* Hbuf  = pre  + (size_t)2 * MTOT * GATES;
  float* h0    = Hbuf + (size_t)MTOT * 128;
  float* fbank = h0   + (size_t)MTOT * NFILT;
  int*   lohi  = (int*)(fbank + NFILT * NBINS);

  k_fbank<<<1, 256, 0, stream>>>(binpoints, fbank, lohi);
  k_feat<<<MTOT / 4, 256, 0, stream>>>(x, fbank, lohi, h0);

  // layer 0 (K=40)
  k_gemm<40, 40><<<dim3(MTOT / 128, GATES / 64, 2), 256, 0, stream>>>(h0, w_ih[0], b_ih[0], b_hh[0], pre);
  k_lstmq<<<dim3(BB, 2), 256, 0, stream>>>(pre, w_hh[0], Hbuf, out, 0);

  // layer 1 (K=128)
  k_gemm<128, 32><<<dim3(MTOT / 128, GATES / 64, 2), 256, 0, stream>>>(Hbuf, w_ih[1], b_ih[1], b_hh[1], pre);
  k_lstmq<<<dim3(BB, 2), 256, 0, stream>>>(pre, w_hh[1], Hbuf, out, 0);

  // layer 2 (K=128)
  k_gemm<128, 32><<<dim3(MTOT / 128, GATES / 64, 2), 256, 0, stream>>>(Hbuf, w_ih[2], b_ih[2], b_hh[2], pre);
  k_lstmq<<<dim3(BB, 2), 256, 0, stream>>>(pre, w_hh[2], Hbuf, out, 1);
}